// Round 13
// baseline (215.798 us; speedup 1.0000x reference)
//
#include <hip/hip_runtime.h>
#include <hip/hip_fp16.h>
#include <cstdint>

#define NT      32768
#define DIN     256
#define DHID    1024
#define DOUT    256
#define NPLANES 8
#define NBLK    (NT / 256)

typedef unsigned short u16;
typedef __attribute__((ext_vector_type(8))) _Float16 f16x8;
typedef __attribute__((ext_vector_type(4))) float    f32x4;

// ---------------- workspace layout (bytes) ----------------
#define WS_OFFSETS 0                           // 9 ints
#define WS_META    64                          // 1 int (ntiles, 64-row granularity)
#define WS_TP      1024                        // <=544 ints
#define WS_TM      (WS_TP + 544*4)
#define WS_BLKHIST (WS_TM + 544*4)
#define WS_BLKBASE (WS_BLKHIST + NBLK*8*4)
#define WS_PERM    (WS_BLKBASE + NBLK*8*4)
#define WS_XB      (WS_PERM + NT*4)            // NT*DIN f16, natural order
#define WS_W1B     (WS_XB + NT*DIN*2)
#define WS_W2B     (WS_W1B + NPLANES*DHID*DIN*2)
#define WS_HB      (WS_W2B + NPLANES*DOUT*DHID*2)   // NT*DHID f16, bucketed

__device__ __forceinline__ u16 f2h_bits(float f) {
    __half h = __float2half(f);
    return *reinterpret_cast<u16*>(&h);
}

__device__ __forceinline__ void gl_lds16(const void* g, void* l) {
    __builtin_amdgcn_global_load_lds(
        (const __attribute__((address_space(1))) void*)g,
        (__attribute__((address_space(3))) void*)l,
        16, 0, 0);
}

// fast gelu: tanh-form, |dev vs exact erf-gelu| <~ 5e-4 (negligible after W2)
__device__ __forceinline__ float gelu_fast(float x) {
    const float u = x * (1.5957691216f + 0.07135481283f * x * x);
    const float e = __expf(-u);
    return x * __builtin_amdgcn_rcpf(1.0f + e);
}

// ---------------- fused prologue: per-block hist + f32->f16 converts ----------
__global__ void prep_k(const int* __restrict__ pidx, const float* __restrict__ x,
                       const float* __restrict__ W1, const float* __restrict__ W2,
                       int* __restrict__ blkhist, u16* __restrict__ xb,
                       u16* __restrict__ w1b, u16* __restrict__ w2b) {
    __shared__ int cnt[NPLANES];
    const int t = threadIdx.x, lane = t & 63;
    if ((int)blockIdx.x < NBLK) {
        if (t < NPLANES) cnt[t] = 0;
        __syncthreads();
        const int p = pidx[blockIdx.x * 256 + t];
#pragma unroll
        for (int q = 0; q < NPLANES; ++q) {
            unsigned long long m = __ballot(p == q);
            if (p == q && __popcll(m & ((1ULL << lane) - 1)) == 0)
                atomicAdd(&cnt[q], __popcll(m));
        }
        __syncthreads();
        if (t < NPLANES) blkhist[blockIdx.x * NPLANES + t] = cnt[t];
    }
    const int n0 = NT * DIN / 4, n1 = NPLANES * DHID * DIN / 4, n2 = NPLANES * DOUT * DHID / 4;
    const int stride = gridDim.x * blockDim.x;
    for (int i = blockIdx.x * blockDim.x + t; i < n0 + n1 + n2; i += stride) {
        const float4* s; ushort4* d; int j;
        if (i < n0)           { s = (const float4*)x;  d = (ushort4*)xb;  j = i; }
        else if (i < n0 + n1) { s = (const float4*)W1; d = (ushort4*)w1b; j = i - n0; }
        else                  { s = (const float4*)W2; d = (ushort4*)w2b; j = i - n0 - n1; }
        float4 v = s[j];
        ushort4 o;
        o.x = f2h_bits(v.x); o.y = f2h_bits(v.y);
        o.z = f2h_bits(v.z); o.w = f2h_bits(v.w);
        d[j] = o;
    }
}

// ---------------- scan: offsets + 64-gran tile list + per-block bases ----------
__global__ void scan_k(const int* __restrict__ blkhist, int* __restrict__ offsets,
                       int* __restrict__ blkbase, int* __restrict__ meta,
                       int* __restrict__ tp, int* __restrict__ tm) {
    __shared__ int tot[NPLANES];
    const int t = threadIdx.x;
    if (t < NPLANES) {
        int s = 0;
#pragma unroll 8
        for (int b = 0; b < NBLK; ++b) s += blkhist[b * NPLANES + t];
        tot[t] = s;
    }
    __syncthreads();
    if (t == 0) {
        int off = 0, tc = 0;
        for (int p = 0; p < NPLANES; ++p) {
            offsets[p] = off;
            for (int m = 0; m < tot[p]; m += 64) { tp[tc] = p; tm[tc] = m; ++tc; }
            off += tot[p];
        }
        offsets[NPLANES] = off;
        meta[0] = tc;
    }
    __syncthreads();
    if (t < NPLANES) {
        int run = offsets[t];
#pragma unroll 8
        for (int b = 0; b < NBLK; ++b) {
            blkbase[b * NPLANES + t] = run;
            run += blkhist[b * NPLANES + t];
        }
    }
}

__global__ void scatter_k(const int* __restrict__ pidx, const int* __restrict__ blkbase,
                          int* __restrict__ perm) {
    __shared__ int wcnt[4][NPLANES];
    __shared__ int wbase[4][NPLANES];
    const int t = threadIdx.x, lane = t & 63, wave = t >> 6;
    const int i = blockIdx.x * 256 + t;
    const int p = pidx[i];
    int rank = 0;
#pragma unroll
    for (int q = 0; q < NPLANES; ++q) {
        unsigned long long m = __ballot(p == q);
        if (lane == 0) wcnt[wave][q] = __popcll(m);
        if (p == q) rank = __popcll(m & ((1ULL << lane) - 1));
    }
    __syncthreads();
    if (t < NPLANES) {
        int run = blkbase[blockIdx.x * NPLANES + t];
#pragma unroll
        for (int w = 0; w < 4; ++w) { wbase[w][t] = run; run += wcnt[w][t]; }
    }
    __syncthreads();
    perm[wbase[wave][p] + rank] = i;
}

// XCD-chunked tile mapping (VERIFIED R6: XCD = linear_block_id % 8).
// NSPLIT sub-blocks of a tile stay on one XCD (consecutive idx -> concurrent).
#define XCD_MAP_HDR(NSPLIT)                                                    \
    const int ntiles = meta[0];                                                \
    const int xcd = blockIdx.x & 7, idx = blockIdx.x >> 3;                     \
    const int q8 = ntiles >> 3, r8 = ntiles & 7;                               \
    const int tn = q8 + (xcd < r8 ? 1 : 0);                                    \
    if (idx >= tn * (NSPLIT)) return;                                          \
    const int tile = (xcd < r8 ? xcd * (q8 + 1)                                \
                               : r8 * (q8 + 1) + (xcd - r8) * q8)              \
                     + idx / (NSPLIT);                                         \
    const int sub = idx % (NSPLIT);

// ---------------- gemm1: R7-exact (64x128 tile, BK=64, 24KB, best 45.4us) ----
__global__ __launch_bounds__(256, 6) void gemm1_k(
    const u16* __restrict__ xb, const u16* __restrict__ w1b,
    const float* __restrict__ b1, const int* __restrict__ perm,
    const int* __restrict__ offsets, const int* __restrict__ meta,
    const int* __restrict__ tp, const int* __restrict__ tm,
    u16* __restrict__ hb)
{
    __shared__ __align__(16) u16 smem[12288];   // sA 8KB | sB 16KB; sOut 16KB reuse
    XCD_MAP_HDR(8)
    const int n0v = sub * 128;
    const int p   = tp[tile];
    const int m0  = tm[tile];
    const int off = offsets[p];
    const int cnt = offsets[p + 1] - off;

    u16* const sA = smem;
    u16* const sB = smem + 4096;

    const int tid = threadIdx.x;
    const u16* aptr[2];
    const u16* bptr[4];
#pragma unroll
    for (int c = 0; c < 2; ++c) {
        const int slot = c * 256 + tid, row = slot >> 3, ch = slot & 7;
        const int gr = min(m0 + row, cnt - 1);
        aptr[c] = xb + (size_t)perm[off + gr] * DIN + ((ch ^ (row & 7)) * 8);
    }
#pragma unroll
    for (int c = 0; c < 4; ++c) {
        const int slot = c * 256 + tid, row = slot >> 3, ch = slot & 7;
        bptr[c] = w1b + ((size_t)p * DHID + n0v + row) * DIN + ((ch ^ (row & 7)) * 8);
    }
    const int wave = tid >> 6, lane = tid & 63;
    const int wr = wave >> 1, wc = wave & 1;    // 2x2 waves, wave tile 32x64
    const int lm = lane & 15, lk = lane >> 4;

    f32x4 acc[2][4];
#pragma unroll
    for (int a = 0; a < 2; ++a)
#pragma unroll
        for (int b = 0; b < 4; ++b) acc[a][b] = (f32x4){0.f, 0.f, 0.f, 0.f};

    for (int kt = 0; kt < DIN / 64; ++kt) {
        const int k0 = kt * 64;
#pragma unroll
        for (int c = 0; c < 2; ++c) gl_lds16(aptr[c] + k0, sA + c * 2048 + tid * 8);
#pragma unroll
        for (int c = 0; c < 4; ++c) gl_lds16(bptr[c] + k0, sB + c * 2048 + tid * 8);
        __syncthreads();
#pragma unroll
        for (int kk = 0; kk < 2; ++kk) {
            f16x8 af[2], bf[4];
#pragma unroll
            for (int mf = 0; mf < 2; ++mf) {
                const int row = wr * 32 + mf * 16 + lm;
                const int g   = kk * 4 + lk;
                af[mf] = *(const f16x8*)(sA + row * 64 + ((g ^ (row & 7)) * 8));
            }
#pragma unroll
            for (int nf = 0; nf < 4; ++nf) {
                const int row = wc * 64 + nf * 16 + lm;
                const int g   = kk * 4 + lk;
                bf[nf] = *(const f16x8*)(sB + row * 64 + ((g ^ (row & 7)) * 8));
            }
#pragma unroll
            for (int mf = 0; mf < 2; ++mf)
#pragma unroll
                for (int nf = 0; nf < 4; ++nf)
                    acc[mf][nf] = __builtin_amdgcn_mfma_f32_16x16x32_f16(
                        af[mf], bf[nf], acc[mf][nf], 0, 0, 0);
        }
        __syncthreads();
    }

    // ---- epilogue: fast gelu -> chunk-swizzled sOut, then coalesced copy-out ----
    u16* const sOut = smem;                     // 64 x 128 u16 = 16KB
#pragma unroll
    for (int nf = 0; nf < 4; ++nf) {
        const int col = wc * 64 + nf * 16 + lm;
        const float bb = b1[p * DHID + n0v + col];
        const int cc = col >> 3, c7 = col & 7;
#pragma unroll
        for (int mf = 0; mf < 2; ++mf) {
#pragma unroll
            for (int j = 0; j < 4; ++j) {
                const int tok = wr * 32 + mf * 16 + lk * 4 + j;
                sOut[tok * 128 + ((cc ^ (tok & 15)) * 8) + c7] =
                    f2h_bits(gelu_fast(acc[mf][nf][j] + bb));
            }
        }
    }
    __syncthreads();
    const int r = tid >> 2, qq = tid & 3;       // 4 threads/row, 64B each
    if (m0 + r < cnt) {
        u16* dst = hb + (size_t)(off + m0 + r) * DHID + n0v;
#pragma unroll
        for (int c = 0; c < 4; ++c) {
            const int l = qq * 4 + c;
            *(int4*)(dst + l * 8) = *(const int4*)(sOut + r * 128 + ((l ^ (r & 15)) * 8));
        }
    }
}

// ---------------- gemm2: split-K (4 segs of 256), 64 tok x 256 out, KT=4 -----
// Each block: one K-segment of one 64-row tile, full DOUT. 4 waves of 64x64.
// Partials combined via f32 atomicAdd into zeroed out (order-independent to
// ~1e-6 << 1.8e-2 threshold). Bias added by seg 0. 40KB LDS -> 4 blocks/CU.
__global__ __launch_bounds__(256, 4) void gemm2_k(
    const u16* __restrict__ hb, const u16* __restrict__ w2b,
    const float* __restrict__ b2, const int* __restrict__ perm,
    const int* __restrict__ offsets, const int* __restrict__ meta,
    const int* __restrict__ tp, const int* __restrict__ tm,
    float* __restrict__ out)
{
    __shared__ __align__(16) u16 smem[20480];   // sA 8KB | sB 32KB
    XCD_MAP_HDR(4)
    const int seg = sub;                        // K segment 0..3
    const int p   = tp[tile];
    const int m0  = tm[tile];
    const int off = offsets[p];
    const int cnt = offsets[p + 1] - off;
    const int kbase = seg * 256;

    u16* const sA = smem;                       // 64 rows x 64k
    u16* const sB = smem + 4096;                // 256 rows x 64k

    const int tid = threadIdx.x, srow = tid >> 3, sch = tid & 7;
    // A: 64 rows x 8 chunks = 512 slots, 2/thread
    const u16* aptr[2];
#pragma unroll
    for (int c = 0; c < 2; ++c) {
        const int row = c * 32 + srow;
        const int gr  = min(m0 + row, cnt - 1);
        aptr[c] = hb + (size_t)(off + gr) * DHID + kbase + ((sch ^ (srow & 7)) * 8);
    }
    // B: 256 rows (all DOUT) x 8 chunks = 2048 slots, 8/thread
    const u16* bptr[8];
#pragma unroll
    for (int c = 0; c < 8; ++c) {
        const int row = c * 32 + srow;
        bptr[c] = w2b + ((size_t)p * DOUT + row) * DHID + kbase + ((sch ^ (srow & 7)) * 8);
    }
    const int wave = tid >> 6, lane = tid & 63;
    const int wc = wave;                        // 1x4 waves, wave tile 64x64
    const int lm = lane & 15, lk = lane >> 4;

    f32x4 acc[4][4];
#pragma unroll
    for (int a = 0; a < 4; ++a)
#pragma unroll
        for (int b = 0; b < 4; ++b) acc[a][b] = (f32x4){0.f, 0.f, 0.f, 0.f};

    for (int kt = 0; kt < 4; ++kt) {            // 4 K-steps of 64 within segment
        const int k0 = kt * 64;
#pragma unroll
        for (int c = 0; c < 2; ++c) gl_lds16(aptr[c] + k0, sA + c * 2048 + tid * 8);
#pragma unroll
        for (int c = 0; c < 8; ++c) gl_lds16(bptr[c] + k0, sB + c * 2048 + tid * 8);
        __syncthreads();
#pragma unroll
        for (int kk = 0; kk < 2; ++kk) {
            const int g = kk * 4 + lk;
            f16x8 af[4];
#pragma unroll
            for (int mf = 0; mf < 4; ++mf) {
                const int row = mf * 16 + lm;
                af[mf] = *(const f16x8*)(sA + row * 64 + ((g ^ (row & 7)) * 8));
            }
#pragma unroll
            for (int nf = 0; nf < 4; ++nf) {
                const int row = wc * 64 + nf * 16 + lm;
                const f16x8 bf = *(const f16x8*)(sB + row * 64 + ((g ^ (row & 7)) * 8));
#pragma unroll
                for (int mf = 0; mf < 4; ++mf)
                    acc[mf][nf] = __builtin_amdgcn_mfma_f32_16x16x32_f16(
                        af[mf], bf, acc[mf][nf], 0, 0, 0);
            }
        }
        __syncthreads();
    }

    // epilogue: atomic accumulate into out (zeroed at stream head); seg0 adds bias
#pragma unroll
    for (int nf = 0; nf < 4; ++nf) {
        const int col = wc * 64 + nf * 16 + lm;
        const float bb = (seg == 0) ? b2[p * DOUT + col] : 0.0f;
#pragma unroll
        for (int mf = 0; mf < 4; ++mf) {
#pragma unroll
            for (int j = 0; j < 4; ++j) {
                const int tok = mf * 16 + lk * 4 + j;
                if (m0 + tok < cnt)
                    atomicAdd(&out[(size_t)perm[off + m0 + tok] * DOUT + col],
                              acc[mf][nf][j] + bb);
            }
        }
    }
}

// ---------------- launch ----------------
extern "C" void kernel_launch(void* const* d_in, const int* in_sizes, int n_in,
                              void* d_out, int out_size, void* d_ws, size_t ws_size,
                              hipStream_t stream) {
    const float* x    = (const float*)d_in[0];
    const float* W1   = (const float*)d_in[1];
    const float* b1   = (const float*)d_in[2];
    const float* W2   = (const float*)d_in[3];
    const float* b2   = (const float*)d_in[4];
    const int*   pidx = (const int*)d_in[5];
    float*       out  = (float*)d_out;

    char* ws      = (char*)d_ws;
    int* offsets  = (int*)(ws + WS_OFFSETS);
    int* meta     = (int*)(ws + WS_META);
    int* tp       = (int*)(ws + WS_TP);
    int* tm       = (int*)(ws + WS_TM);
    int* blkhist  = (int*)(ws + WS_BLKHIST);
    int* blkbase  = (int*)(ws + WS_BLKBASE);
    int* perm     = (int*)(ws + WS_PERM);
    u16* xb       = (u16*)(ws + WS_XB);
    u16* w1b      = (u16*)(ws + WS_W1B);
    u16* w2b      = (u16*)(ws + WS_W2B);
    u16* hb       = (u16*)(ws + WS_HB);

    // zero out early; overlaps with prep (gemm2 atomically accumulates into it)
    hipMemsetAsync(out, 0, (size_t)out_size * sizeof(float), stream);

    prep_k<<<2048, 256, 0, stream>>>(pidx, x, W1, W2, blkhist, xb, w1b, w2b);
    scan_k<<<1, 64, 0, stream>>>(blkhist, offsets, blkbase, meta, tp, tm);
    scatter_k<<<NBLK, 256, 0, stream>>>(pidx, blkbase, perm);

    // 64-gran tiles: ntiles <= 528 -> tn <= 68/xcd
    // gemm1: NSPLIT=8 (128-col chunks of DHID) -> 8*68*8 = 4352 slots
    gemm1_k<<<4352, 256, 0, stream>>>(xb, w1b, b1, perm, offsets, meta, tp, tm, hb);
    // gemm2: NSPLIT=4 (K segments of 256)      -> 8*68*4 = 2176 slots
    gemm2_k<<<2176, 256, 0, stream>>>(hb, w2b, b2, perm, offsets, meta, tp, tm, out);
}

// Round 14
// 120.388 us; speedup vs baseline: 1.7925x; 1.7925x over previous
//
#include <hip/hip_runtime.h>
#include <hip/hip_fp16.h>
#include <cstdint>

#define NT      32768
#define DIN     256
#define DHID    1024
#define DOUT    256
#define NPLANES 8
#define NBLK    (NT / 256)

typedef unsigned short u16;
typedef __attribute__((ext_vector_type(8))) _Float16 f16x8;
typedef __attribute__((ext_vector_type(4))) float    f32x4;

// ---------------- workspace layout (bytes) ----------------
#define WS_OFFSETS 0                           // 9 ints
#define WS_META    64                          // 1 int (ntiles, 64-row granularity)
#define WS_TP      1024                        // <=544 ints
#define WS_TM      (WS_TP + 544*4)
#define WS_BLKHIST (WS_TM + 544*4)
#define WS_BLKBASE (WS_BLKHIST + NBLK*8*4)
#define WS_PERM    (WS_BLKBASE + NBLK*8*4)
#define WS_XB      (WS_PERM + NT*4)            // NT*DIN f16, natural order
#define WS_W1B     (WS_XB + NT*DIN*2)
#define WS_W2B     (WS_W1B + NPLANES*DHID*DIN*2)
#define WS_HB      (WS_W2B + NPLANES*DOUT*DHID*2)   // NT*DHID f16, bucketed

__device__ __forceinline__ u16 f2h_bits(float f) {
    __half h = __float2half(f);
    return *reinterpret_cast<u16*>(&h);
}

__device__ __forceinline__ void gl_lds16(const void* g, void* l) {
    __builtin_amdgcn_global_load_lds(
        (const __attribute__((address_space(1))) void*)g,
        (__attribute__((address_space(3))) void*)l,
        16, 0, 0);
}

// fast gelu: tanh-form, |dev vs exact erf-gelu| <~ 5e-4 (negligible after W2)
__device__ __forceinline__ float gelu_fast(float x) {
    const float u = x * (1.5957691216f + 0.07135481283f * x * x);
    const float e = __expf(-u);
    return x * __builtin_amdgcn_rcpf(1.0f + e);
}

// ---------------- fused prologue: per-block hist + f32->f16 converts ----------
__global__ void prep_k(const int* __restrict__ pidx, const float* __restrict__ x,
                       const float* __restrict__ W1, const float* __restrict__ W2,
                       int* __restrict__ blkhist, u16* __restrict__ xb,
                       u16* __restrict__ w1b, u16* __restrict__ w2b) {
    __shared__ int cnt[NPLANES];
    const int t = threadIdx.x, lane = t & 63;
    if ((int)blockIdx.x < NBLK) {
        if (t < NPLANES) cnt[t] = 0;
        __syncthreads();
        const int p = pidx[blockIdx.x * 256 + t];
#pragma unroll
        for (int q = 0; q < NPLANES; ++q) {
            unsigned long long m = __ballot(p == q);
            if (p == q && __popcll(m & ((1ULL << lane) - 1)) == 0)
                atomicAdd(&cnt[q], __popcll(m));
        }
        __syncthreads();
        if (t < NPLANES) blkhist[blockIdx.x * NPLANES + t] = cnt[t];
    }
    const int n0 = NT * DIN / 4, n1 = NPLANES * DHID * DIN / 4, n2 = NPLANES * DOUT * DHID / 4;
    const int stride = gridDim.x * blockDim.x;
    for (int i = blockIdx.x * blockDim.x + t; i < n0 + n1 + n2; i += stride) {
        const float4* s; ushort4* d; int j;
        if (i < n0)           { s = (const float4*)x;  d = (ushort4*)xb;  j = i; }
        else if (i < n0 + n1) { s = (const float4*)W1; d = (ushort4*)w1b; j = i - n0; }
        else                  { s = (const float4*)W2; d = (ushort4*)w2b; j = i - n0 - n1; }
        float4 v = s[j];
        ushort4 o;
        o.x = f2h_bits(v.x); o.y = f2h_bits(v.y);
        o.z = f2h_bits(v.z); o.w = f2h_bits(v.w);
        d[j] = o;
    }
}

// ---------------- scan: offsets + 64-gran tile list + per-block bases ----------
__global__ void scan_k(const int* __restrict__ blkhist, int* __restrict__ offsets,
                       int* __restrict__ blkbase, int* __restrict__ meta,
                       int* __restrict__ tp, int* __restrict__ tm) {
    __shared__ int tot[NPLANES];
    const int t = threadIdx.x;
    if (t < NPLANES) {
        int s = 0;
#pragma unroll 8
        for (int b = 0; b < NBLK; ++b) s += blkhist[b * NPLANES + t];
        tot[t] = s;
    }
    __syncthreads();
    if (t == 0) {
        int off = 0, tc = 0;
        for (int p = 0; p < NPLANES; ++p) {
            offsets[p] = off;
            for (int m = 0; m < tot[p]; m += 64) { tp[tc] = p; tm[tc] = m; ++tc; }
            off += tot[p];
        }
        offsets[NPLANES] = off;
        meta[0] = tc;
    }
    __syncthreads();
    if (t < NPLANES) {
        int run = offsets[t];
#pragma unroll 8
        for (int b = 0; b < NBLK; ++b) {
            blkbase[b * NPLANES + t] = run;
            run += blkhist[b * NPLANES + t];
        }
    }
}

__global__ void scatter_k(const int* __restrict__ pidx, const int* __restrict__ blkbase,
                          int* __restrict__ perm) {
    __shared__ int wcnt[4][NPLANES];
    __shared__ int wbase[4][NPLANES];
    const int t = threadIdx.x, lane = t & 63, wave = t >> 6;
    const int i = blockIdx.x * 256 + t;
    const int p = pidx[i];
    int rank = 0;
#pragma unroll
    for (int q = 0; q < NPLANES; ++q) {
        unsigned long long m = __ballot(p == q);
        if (lane == 0) wcnt[wave][q] = __popcll(m);
        if (p == q) rank = __popcll(m & ((1ULL << lane) - 1));
    }
    __syncthreads();
    if (t < NPLANES) {
        int run = blkbase[blockIdx.x * NPLANES + t];
#pragma unroll
        for (int w = 0; w < 4; ++w) { wbase[w][t] = run; run += wcnt[w][t]; }
    }
    __syncthreads();
    perm[wbase[wave][p] + rank] = i;
}

// ---------------- gemm1: persistent-B blocks ---------------------------------
// Grid 512 = 8 planes (pinned to XCD via bid&7, verified R6) x 8 col-chunks x
// 8 m-groups. Each block stages its W1 chunk (128 cols x 256 K = 64KB) ONCE,
// then loops m-tiles (stride 8): prefetch-A(8KB) -> compute -> sync.
// LDS 80KB dynamic -> 2 blocks/CU. Cuts B-staging 270MB -> 33MB.
__global__ __launch_bounds__(256, 2) void gemm1_k(
    const u16* __restrict__ xb, const u16* __restrict__ w1b,
    const float* __restrict__ b1, const int* __restrict__ perm,
    const int* __restrict__ offsets, u16* __restrict__ hb)
{
    extern __shared__ __align__(16) u16 smem[];  // sB 64KB | sA0 8KB | sA1 8KB
    u16* const sB  = smem;                       // 32768 u16
    u16* const sA0 = smem + 32768;               // 4096 u16
    u16* const sA1 = smem + 36864;

    const int p     = blockIdx.x & 7;            // plane == XCD
    const int chunk = (blockIdx.x >> 3) & 7;
    const int mg    = blockIdx.x >> 6;           // 0..7
    const int off = offsets[p];
    const int cnt = offsets[p + 1] - off;
    if (cnt <= 0) return;
    const int nt  = (cnt + 63) >> 6;
    const int n0v = chunk * 128;

    const int tid = threadIdx.x;
    const int wave = tid >> 6, lane = tid & 63;
    const int wr = wave >> 1, wc = wave & 1;     // 2x2 waves, wave tile 32x64
    const int lm = lane & 15, lk = lane >> 4;

    // ---- stage B once: 128 rows x 256 K, 4096 x 16B chunks, 16/thread.
    // swizzle: src chunk = ch ^ (row&31) so linear LDS dest = swizzled layout.
    {
        const u16* wbase = w1b + ((size_t)p * DHID + n0v) * DIN;
#pragma unroll
        for (int c = 0; c < 16; ++c) {
            const int slot = c * 256 + tid;
            const int row = slot >> 5, ch = slot & 31;
            gl_lds16(wbase + row * DIN + ((ch ^ (row & 31)) * 8), sB + slot * 8);
        }
    }

    // per-thread A staging geometry (2 chunks/thread, 8 chunks/row)
    const int ar0 = tid >> 3,        ac0 = tid & 7;
    const int ar1 = (256 + tid) >> 3, ac1 = (256 + tid) & 7;

#define STAGE_A(buf, a0p, a1p, kt) do {                                        \
        gl_lds16((a0p) + (kt) * 64, (buf) + tid * 8);                          \
        gl_lds16((a1p) + (kt) * 64, (buf) + 2048 + tid * 8); } while (0)

#define COMPUTE1(buf, kt) do {                                                 \
        _Pragma("unroll") for (int kk = 0; kk < 2; ++kk) {                     \
            const int g = kk * 4 + lk;                                         \
            f16x8 af[2], bf[4];                                                \
            _Pragma("unroll") for (int mf = 0; mf < 2; ++mf) {                 \
                const int r = wr * 32 + mf * 16 + lm;                          \
                af[mf] = *(const f16x8*)((buf) + r * 64 + ((g ^ (r & 7)) * 8));\
            }                                                                  \
            _Pragma("unroll") for (int nf = 0; nf < 4; ++nf) {                 \
                const int r = wc * 64 + nf * 16 + lm;                          \
                const int cci = (kt) * 8 + g;                                  \
                bf[nf] = *(const f16x8*)(sB + r * 256 + ((cci ^ (r & 31)) * 8));\
            }                                                                  \
            _Pragma("unroll") for (int mf = 0; mf < 2; ++mf)                   \
                _Pragma("unroll") for (int nf = 0; nf < 4; ++nf)               \
                    acc[mf][nf] = __builtin_amdgcn_mfma_f32_16x16x32_f16(      \
                        af[mf], bf[nf], acc[mf][nf], 0, 0, 0);                 \
        } } while (0)

    for (int mt = mg; mt < nt; mt += 8) {
        const int m0 = mt * 64;
        const u16* a0 = xb + (size_t)perm[off + min(m0 + ar0, cnt - 1)] * DIN
                           + ((ac0 ^ (ar0 & 7)) * 8);
        const u16* a1 = xb + (size_t)perm[off + min(m0 + ar1, cnt - 1)] * DIN
                           + ((ac1 ^ (ar1 & 7)) * 8);

        f32x4 acc[2][4];
#pragma unroll
        for (int a = 0; a < 2; ++a)
#pragma unroll
            for (int b = 0; b < 4; ++b) acc[a][b] = (f32x4){0.f, 0.f, 0.f, 0.f};

        STAGE_A(sA0, a0, a1, 0);
        __syncthreads();                 // A0 ready (first iter: B also drained)

#pragma unroll
        for (int kt = 0; kt < 4; ++kt) {
            u16* const cur = (kt & 1) ? sA1 : sA0;
            u16* const nxt = (kt & 1) ? sA0 : sA1;
            if (kt < 3) STAGE_A(nxt, a0, a1, kt + 1);   // prefetch before compute
            COMPUTE1(cur, kt);
            __syncthreads();             // drain (post-compute) + readers done
        }

        // ---- epilogue: gelu -> swizzled sOut (16KB over sA0+sA1), copy-out
        u16* const sOut = sA0;           // 64 x 128 u16
#pragma unroll
        for (int nf = 0; nf < 4; ++nf) {
            const int col = wc * 64 + nf * 16 + lm;
            const float bb = b1[p * DHID + n0v + col];
            const int cc = col >> 3, c7 = col & 7;
#pragma unroll
            for (int mf = 0; mf < 2; ++mf) {
#pragma unroll
                for (int j = 0; j < 4; ++j) {
                    const int tok = wr * 32 + mf * 16 + lk * 4 + j;
                    sOut[tok * 128 + ((cc ^ (tok & 15)) * 8) + c7] =
                        f2h_bits(gelu_fast(acc[mf][nf][j] + bb));
                }
            }
        }
        __syncthreads();
        const int r = tid >> 2, qq = tid & 3;    // 4 threads/row, 64B each
        if (m0 + r < cnt) {
            u16* dst = hb + (size_t)(off + m0 + r) * DHID + n0v;
#pragma unroll
            for (int c = 0; c < 4; ++c) {
                const int l = qq * 4 + c;
                *(int4*)(dst + l * 8) = *(const int4*)(sOut + r * 128 + ((l ^ (r & 15)) * 8));
            }
        }
        __syncthreads();                 // copy-out reads done before next STAGE_A
    }
#undef STAGE_A
#undef COMPUTE1
}

// XCD-chunked tile mapping (VERIFIED R6: XCD = linear_block_id % 8).
#define XCD_MAP(NSPLIT)                                                        \
    const int ntiles = meta[0];                                                \
    const int xcd = blockIdx.x & 7, idx = blockIdx.x >> 3;                     \
    const int q8 = ntiles >> 3, r8 = ntiles & 7;                               \
    const int tn = q8 + (xcd < r8 ? 1 : 0);                                    \
    if (idx >= tn * (NSPLIT)) return;                                          \
    const int tile = (xcd < r8 ? xcd * (q8 + 1)                                \
                               : r8 * (q8 + 1) + (xcd - r8) * q8)              \
                     + idx / (NSPLIT);                                         \
    const int n0v = (idx % (NSPLIT)) * 128;

// ---------------- gemm2: R9-exact (64x128 tile, BK=128, KT=8, 48KB) ----------
__global__ __launch_bounds__(256, 3) void gemm2_k(
    const u16* __restrict__ hb, const u16* __restrict__ w2b,
    const float* __restrict__ b2, const int* __restrict__ perm,
    const int* __restrict__ offsets, const int* __restrict__ meta,
    const int* __restrict__ tp, const int* __restrict__ tm,
    float* __restrict__ out)
{
    __shared__ __align__(16) u16 smem[24576];   // sA 16KB | sB 32KB
    XCD_MAP(2)
    const int p   = tp[tile];
    const int m0  = tm[tile];
    const int off = offsets[p];
    const int cnt = offsets[p + 1] - off;

    u16* const sA = smem;
    u16* const sB = smem + 8192;

    const int tid = threadIdx.x;
    const u16* aptr[4];
#pragma unroll
    for (int c = 0; c < 4; ++c) {
        const int slot = c * 256 + tid, row = slot >> 4, ch = slot & 15;
        aptr[c] = hb + (size_t)(off + min(m0 + row, cnt - 1)) * DHID + ((ch ^ (row & 15)) * 8);
    }
    const u16* bptr[8];
#pragma unroll
    for (int c = 0; c < 8; ++c) {
        const int slot = c * 256 + tid, row = slot >> 4, ch = slot & 15;
        bptr[c] = w2b + ((size_t)p * DOUT + n0v + row) * DHID + ((ch ^ (row & 15)) * 8);
    }
    const int wave = tid >> 6, lane = tid & 63;
    const int wr = wave >> 1, wc = wave & 1;    // 2x2 waves, wave tile 32x64
    const int lm = lane & 15, lk = lane >> 4;

    f32x4 acc[2][4];
#pragma unroll
    for (int a = 0; a < 2; ++a)
#pragma unroll
        for (int b = 0; b < 4; ++b) acc[a][b] = (f32x4){0.f, 0.f, 0.f, 0.f};

    for (int kt = 0; kt < DHID / 128; ++kt) {   // 8 K-steps
        const int k0 = kt * 128;
#pragma unroll
        for (int c = 0; c < 4; ++c) gl_lds16(aptr[c] + k0, sA + c * 2048 + tid * 8);
#pragma unroll
        for (int c = 0; c < 8; ++c) gl_lds16(bptr[c] + k0, sB + c * 2048 + tid * 8);
        __syncthreads();
#pragma unroll
        for (int kk = 0; kk < 4; ++kk) {
            f16x8 af[2], bf[4];
#pragma unroll
            for (int mf = 0; mf < 2; ++mf) {
                const int row = wr * 32 + mf * 16 + lm;
                const int g   = kk * 4 + lk;
                af[mf] = *(const f16x8*)(sA + row * 128 + ((g ^ (row & 15)) * 8));
            }
#pragma unroll
            for (int nf = 0; nf < 4; ++nf) {
                const int row = wc * 64 + nf * 16 + lm;
                const int g   = kk * 4 + lk;
                bf[nf] = *(const f16x8*)(sB + row * 128 + ((g ^ (row & 15)) * 8));
            }
#pragma unroll
            for (int mf = 0; mf < 2; ++mf)
#pragma unroll
                for (int nf = 0; nf < 4; ++nf)
                    acc[mf][nf] = __builtin_amdgcn_mfma_f32_16x16x32_f16(
                        af[mf], bf[nf], acc[mf][nf], 0, 0, 0);
        }
        __syncthreads();
    }

#pragma unroll
    for (int nf = 0; nf < 4; ++nf) {
        const int col = n0v + wc * 64 + nf * 16 + lm;
        const float bb = b2[p * DOUT + col];
#pragma unroll
        for (int mf = 0; mf < 2; ++mf) {
#pragma unroll
            for (int j = 0; j < 4; ++j) {
                const int tok = wr * 32 + mf * 16 + lk * 4 + j;
                if (m0 + tok < cnt)
                    out[(size_t)perm[off + m0 + tok] * DOUT + col] = acc[mf][nf][j] + bb;
            }
        }
    }
}

// ---------------- launch ----------------
extern "C" void kernel_launch(void* const* d_in, const int* in_sizes, int n_in,
                              void* d_out, int out_size, void* d_ws, size_t ws_size,
                              hipStream_t stream) {
    const float* x    = (const float*)d_in[0];
    const float* W1   = (const float*)d_in[1];
    const float* b1   = (const float*)d_in[2];
    const float* W2   = (const float*)d_in[3];
    const float* b2   = (const float*)d_in[4];
    const int*   pidx = (const int*)d_in[5];
    float*       out  = (float*)d_out;

    char* ws      = (char*)d_ws;
    int* offsets  = (int*)(ws + WS_OFFSETS);
    int* meta     = (int*)(ws + WS_META);
    int* tp       = (int*)(ws + WS_TP);
    int* tm       = (int*)(ws + WS_TM);
    int* blkhist  = (int*)(ws + WS_BLKHIST);
    int* blkbase  = (int*)(ws + WS_BLKBASE);
    int* perm     = (int*)(ws + WS_PERM);
    u16* xb       = (u16*)(ws + WS_XB);
    u16* w1b      = (u16*)(ws + WS_W1B);
    u16* w2b      = (u16*)(ws + WS_W2B);
    u16* hb       = (u16*)(ws + WS_HB);

    // allow 80KB dynamic LDS for gemm1 (idempotent)
    (void)hipFuncSetAttribute((const void*)gemm1_k,
                              hipFuncAttributeMaxDynamicSharedMemorySize, 81920);

    prep_k<<<2048, 256, 0, stream>>>(pidx, x, W1, W2, blkhist, xb, w1b, w2b);
    scan_k<<<1, 64, 0, stream>>>(blkhist, offsets, blkbase, meta, tp, tm);
    scatter_k<<<NBLK, 256, 0, stream>>>(pidx, blkbase, perm);

    // gemm1: persistent-B, 8 planes x 8 chunks x 8 m-groups
    gemm1_k<<<512, 256, 81920, stream>>>(xb, w1b, b1, perm, offsets, hb);
    // gemm2: 64-gran tiles, NSPLIT=2 -> 8*66*2 = 1056 slots
    gemm2_k<<<1056, 256, 0, stream>>>(hb, w2b, b2, perm, offsets, meta, tp, tm, out);
}

// Round 15
// 110.068 us; speedup vs baseline: 1.9606x; 1.0938x over previous
//
#include <hip/hip_runtime.h>
#include <hip/hip_fp16.h>
#include <cstdint>

#define NT      32768
#define DIN     256
#define DHID    1024
#define DOUT    256
#define NPLANES 8
#define NBLK    (NT / 256)

typedef unsigned short u16;
typedef __attribute__((ext_vector_type(8))) _Float16 f16x8;
typedef __attribute__((ext_vector_type(4))) float    f32x4;

// ---------------- workspace layout (bytes) ----------------
#define WS_OFFSETS 0                           // 9 ints (written by scatter_k blk 0)
#define WS_BLKHIST 64                          // NBLK*8 ints
#define WS_PERM    (WS_BLKHIST + NBLK*8*4)     // NT ints
#define WS_XB      (WS_PERM + NT*4)            // NT*DIN f16, natural order
#define WS_W1B     (WS_XB + NT*DIN*2)
#define WS_W2B     (WS_W1B + NPLANES*DHID*DIN*2)
#define WS_HB      (WS_W2B + NPLANES*DOUT*DHID*2)   // NT*DHID f16, bucketed

__device__ __forceinline__ u16 f2h_bits(float f) {
    __half h = __float2half(f);
    return *reinterpret_cast<u16*>(&h);
}

__device__ __forceinline__ void gl_lds16(const void* g, void* l) {
    __builtin_amdgcn_global_load_lds(
        (const __attribute__((address_space(1))) void*)g,
        (__attribute__((address_space(3))) void*)l,
        16, 0, 0);
}

// fast gelu: tanh-form, |dev vs exact erf-gelu| <~ 5e-4 (negligible after W2)
__device__ __forceinline__ float gelu_fast(float x) {
    const float u = x * (1.5957691216f + 0.07135481283f * x * x);
    const float e = __expf(-u);
    return x * __builtin_amdgcn_rcpf(1.0f + e);
}

// ---------------- prep: per-block hist + f32->f16 converts ----------
__global__ void prep_k(const int* __restrict__ pidx, const float* __restrict__ x,
                       const float* __restrict__ W1, const float* __restrict__ W2,
                       int* __restrict__ blkhist, u16* __restrict__ xb,
                       u16* __restrict__ w1b, u16* __restrict__ w2b) {
    __shared__ int cnt[NPLANES];
    const int t = threadIdx.x, lane = t & 63;
    if ((int)blockIdx.x < NBLK) {
        if (t < NPLANES) cnt[t] = 0;
        __syncthreads();
        const int p = pidx[blockIdx.x * 256 + t];
#pragma unroll
        for (int q = 0; q < NPLANES; ++q) {
            unsigned long long m = __ballot(p == q);
            if (p == q && __popcll(m & ((1ULL << lane) - 1)) == 0)
                atomicAdd(&cnt[q], __popcll(m));
        }
        __syncthreads();
        if (t < NPLANES) blkhist[blockIdx.x * NPLANES + t] = cnt[t];
    }
    const int n0 = NT * DIN / 4, n1 = NPLANES * DHID * DIN / 4, n2 = NPLANES * DOUT * DHID / 4;
    const int stride = gridDim.x * blockDim.x;
    for (int i = blockIdx.x * blockDim.x + t; i < n0 + n1 + n2; i += stride) {
        const float4* s; ushort4* d; int j;
        if (i < n0)           { s = (const float4*)x;  d = (ushort4*)xb;  j = i; }
        else if (i < n0 + n1) { s = (const float4*)W1; d = (ushort4*)w1b; j = i - n0; }
        else                  { s = (const float4*)W2; d = (ushort4*)w2b; j = i - n0 - n1; }
        float4 v = s[j];
        ushort4 o;
        o.x = f2h_bits(v.x); o.y = f2h_bits(v.y);
        o.z = f2h_bits(v.z); o.w = f2h_bits(v.w);
        d[j] = o;
    }
}

// ---------------- scatter with inline scan (replaces scan_k + scatter_k) ------
// Each block computes plane totals + its own prefix from blkhist (4KB, L2-hot);
// block 0 publishes offsets[9] for the gemm kernels (kernel-boundary ordering).
__global__ void scatter_k(const int* __restrict__ pidx, const int* __restrict__ blkhist,
                          int* __restrict__ offsets, int* __restrict__ perm) {
    __shared__ int stot[NPLANES], spre[NPLANES], sbase[NPLANES];
    __shared__ int wcnt[4][NPLANES], wbase[4][NPLANES];
    const int t = threadIdx.x, lane = t & 63, wave = t >> 6;
    if (t < NPLANES) {
        int tot = 0, pre = 0;
        for (int b = 0; b < NBLK; ++b) {
            const int v = blkhist[b * NPLANES + t];
            tot += v;
            if (b < (int)blockIdx.x) pre += v;
        }
        stot[t] = tot; spre[t] = pre;
    }
    __syncthreads();
    if (t == 0) {
        int run = 0;
        for (int q = 0; q < NPLANES; ++q) {
            sbase[q] = run + spre[q];
            if (blockIdx.x == 0) offsets[q] = run;
            run += stot[q];
        }
        if (blockIdx.x == 0) offsets[NPLANES] = run;
    }
    __syncthreads();
    const int i = blockIdx.x * 256 + t;
    const int p = pidx[i];
    int rank = 0;
#pragma unroll
    for (int q = 0; q < NPLANES; ++q) {
        unsigned long long m = __ballot(p == q);
        if (lane == 0) wcnt[wave][q] = __popcll(m);
        if (p == q) rank = __popcll(m & ((1ULL << lane) - 1));
    }
    __syncthreads();
    if (t < NPLANES) {
        int run = sbase[t];
#pragma unroll
        for (int w = 0; w < 4; ++w) { wbase[w][t] = run; run += wcnt[w][t]; }
    }
    __syncthreads();
    perm[wbase[wave][p] + rank] = i;
}

// Self-derived tile map (no tile arrays): ntiles + tile->(p,m0) from offsets[9].
// XCD-chunked (VERIFIED R6: XCD = linear_block_id % 8); NSPLIT sub-blocks of a
// tile stay on one XCD. All wave-uniform scalar ops, no runtime-indexed arrays.
#define TILE_MAP(NSPLIT)                                                       \
    int ntiles = 0;                                                            \
    _Pragma("unroll") for (int q_ = 0; q_ < NPLANES; ++q_)                     \
        ntiles += (offsets[q_ + 1] - offsets[q_] + 63) >> 6;                   \
    const int xcd = blockIdx.x & 7, idx = blockIdx.x >> 3;                     \
    const int q8 = ntiles >> 3, r8 = ntiles & 7;                               \
    const int tn = q8 + (xcd < r8 ? 1 : 0);                                    \
    if (idx >= tn * (NSPLIT)) return;                                          \
    const int tile = (xcd < r8 ? xcd * (q8 + 1)                                \
                               : r8 * (q8 + 1) + (xcd - r8) * q8)              \
                     + idx / (NSPLIT);                                         \
    const int sub = idx % (NSPLIT);                                            \
    int p = 0, m0 = 0, pre_ = 0;                                               \
    _Pragma("unroll") for (int q_ = 0; q_ < NPLANES; ++q_) {                   \
        const int ntq = (offsets[q_ + 1] - offsets[q_] + 63) >> 6;             \
        if (tile >= pre_ && tile < pre_ + ntq) { p = q_; m0 = (tile - pre_) * 64; } \
        pre_ += ntq;                                                           \
    }                                                                          \
    const int off = offsets[p];                                                \
    const int cnt = offsets[p + 1] - off;

// ---------------- gemm1: R7-exact (64x128 tile, BK=64, 24KB, best 45.4us) ----
__global__ __launch_bounds__(256, 6) void gemm1_k(
    const u16* __restrict__ xb, const u16* __restrict__ w1b,
    const float* __restrict__ b1, const int* __restrict__ perm,
    const int* __restrict__ offsets, u16* __restrict__ hb)
{
    __shared__ __align__(16) u16 smem[12288];   // sA 8KB | sB 16KB; sOut 16KB reuse
    TILE_MAP(8)
    const int n0v = sub * 128;

    u16* const sA = smem;
    u16* const sB = smem + 4096;

    const int tid = threadIdx.x;
    const u16* aptr[2];
    const u16* bptr[4];
#pragma unroll
    for (int c = 0; c < 2; ++c) {
        const int slot = c * 256 + tid, row = slot >> 3, ch = slot & 7;
        const int gr = min(m0 + row, cnt - 1);
        aptr[c] = xb + (size_t)perm[off + gr] * DIN + ((ch ^ (row & 7)) * 8);
    }
#pragma unroll
    for (int c = 0; c < 4; ++c) {
        const int slot = c * 256 + tid, row = slot >> 3, ch = slot & 7;
        bptr[c] = w1b + ((size_t)p * DHID + n0v + row) * DIN + ((ch ^ (row & 7)) * 8);
    }
    const int wave = tid >> 6, lane = tid & 63;
    const int wr = wave >> 1, wc = wave & 1;    // 2x2 waves, wave tile 32x64
    const int lm = lane & 15, lk = lane >> 4;

    f32x4 acc[2][4];
#pragma unroll
    for (int a = 0; a < 2; ++a)
#pragma unroll
        for (int b = 0; b < 4; ++b) acc[a][b] = (f32x4){0.f, 0.f, 0.f, 0.f};

    for (int kt = 0; kt < DIN / 64; ++kt) {
        const int k0 = kt * 64;
#pragma unroll
        for (int c = 0; c < 2; ++c) gl_lds16(aptr[c] + k0, sA + c * 2048 + tid * 8);
#pragma unroll
        for (int c = 0; c < 4; ++c) gl_lds16(bptr[c] + k0, sB + c * 2048 + tid * 8);
        __syncthreads();
#pragma unroll
        for (int kk = 0; kk < 2; ++kk) {
            f16x8 af[2], bf[4];
#pragma unroll
            for (int mf = 0; mf < 2; ++mf) {
                const int row = wr * 32 + mf * 16 + lm;
                const int g   = kk * 4 + lk;
                af[mf] = *(const f16x8*)(sA + row * 64 + ((g ^ (row & 7)) * 8));
            }
#pragma unroll
            for (int nf = 0; nf < 4; ++nf) {
                const int row = wc * 64 + nf * 16 + lm;
                const int g   = kk * 4 + lk;
                bf[nf] = *(const f16x8*)(sB + row * 64 + ((g ^ (row & 7)) * 8));
            }
#pragma unroll
            for (int mf = 0; mf < 2; ++mf)
#pragma unroll
                for (int nf = 0; nf < 4; ++nf)
                    acc[mf][nf] = __builtin_amdgcn_mfma_f32_16x16x32_f16(
                        af[mf], bf[nf], acc[mf][nf], 0, 0, 0);
        }
        __syncthreads();
    }

    // ---- epilogue: fast gelu -> chunk-swizzled sOut, then coalesced copy-out ----
    u16* const sOut = smem;                     // 64 x 128 u16 = 16KB
#pragma unroll
    for (int nf = 0; nf < 4; ++nf) {
        const int col = wc * 64 + nf * 16 + lm;
        const float bb = b1[p * DHID + n0v + col];
        const int cc = col >> 3, c7 = col & 7;
#pragma unroll
        for (int mf = 0; mf < 2; ++mf) {
#pragma unroll
            for (int j = 0; j < 4; ++j) {
                const int tok = wr * 32 + mf * 16 + lk * 4 + j;
                sOut[tok * 128 + ((cc ^ (tok & 15)) * 8) + c7] =
                    f2h_bits(gelu_fast(acc[mf][nf][j] + bb));
            }
        }
    }
    __syncthreads();
    const int r = tid >> 2, qq = tid & 3;       // 4 threads/row, 64B each
    if (m0 + r < cnt) {
        u16* dst = hb + (size_t)(off + m0 + r) * DHID + n0v;
#pragma unroll
        for (int c = 0; c < 4; ++c) {
            const int l = qq * 4 + c;
            *(int4*)(dst + l * 8) = *(const int4*)(sOut + r * 128 + ((l ^ (r & 15)) * 8));
        }
    }
}

// ---------------- gemm2: R9-exact (64x128 tile, BK=128, KT=8, 48KB) ----------
__global__ __launch_bounds__(256, 3) void gemm2_k(
    const u16* __restrict__ hb, const u16* __restrict__ w2b,
    const float* __restrict__ b2, const int* __restrict__ perm,
    const int* __restrict__ offsets, float* __restrict__ out)
{
    __shared__ __align__(16) u16 smem[24576];   // sA 16KB | sB 32KB
    TILE_MAP(2)
    const int n0v = sub * 128;

    u16* const sA = smem;
    u16* const sB = smem + 8192;

    const int tid = threadIdx.x;
    const u16* aptr[4];
#pragma unroll
    for (int c = 0; c < 4; ++c) {
        const int slot = c * 256 + tid, row = slot >> 4, ch = slot & 15;
        aptr[c] = hb + (size_t)(off + min(m0 + row, cnt - 1)) * DHID + ((ch ^ (row & 15)) * 8);
    }
    const u16* bptr[8];
#pragma unroll
    for (int c = 0; c < 8; ++c) {
        const int slot = c * 256 + tid, row = slot >> 4, ch = slot & 15;
        bptr[c] = w2b + ((size_t)p * DOUT + n0v + row) * DHID + ((ch ^ (row & 15)) * 8);
    }
    const int wave = tid >> 6, lane = tid & 63;
    const int wr = wave >> 1, wc = wave & 1;    // 2x2 waves, wave tile 32x64
    const int lm = lane & 15, lk = lane >> 4;

    f32x4 acc[2][4];
#pragma unroll
    for (int a = 0; a < 2; ++a)
#pragma unroll
        for (int b = 0; b < 4; ++b) acc[a][b] = (f32x4){0.f, 0.f, 0.f, 0.f};

    for (int kt = 0; kt < DHID / 128; ++kt) {   // 8 K-steps
        const int k0 = kt * 128;
#pragma unroll
        for (int c = 0; c < 4; ++c) gl_lds16(aptr[c] + k0, sA + c * 2048 + tid * 8);
#pragma unroll
        for (int c = 0; c < 8; ++c) gl_lds16(bptr[c] + k0, sB + c * 2048 + tid * 8);
        __syncthreads();
#pragma unroll
        for (int kk = 0; kk < 4; ++kk) {
            f16x8 af[2], bf[4];
#pragma unroll
            for (int mf = 0; mf < 2; ++mf) {
                const int row = wr * 32 + mf * 16 + lm;
                const int g   = kk * 4 + lk;
                af[mf] = *(const f16x8*)(sA + row * 128 + ((g ^ (row & 15)) * 8));
            }
#pragma unroll
            for (int nf = 0; nf < 4; ++nf) {
                const int row = wc * 64 + nf * 16 + lm;
                const int g   = kk * 4 + lk;
                bf[nf] = *(const f16x8*)(sB + row * 128 + ((g ^ (row & 15)) * 8));
            }
#pragma unroll
            for (int mf = 0; mf < 2; ++mf)
#pragma unroll
                for (int nf = 0; nf < 4; ++nf)
                    acc[mf][nf] = __builtin_amdgcn_mfma_f32_16x16x32_f16(
                        af[mf], bf[nf], acc[mf][nf], 0, 0, 0);
        }
        __syncthreads();
    }

#pragma unroll
    for (int nf = 0; nf < 4; ++nf) {
        const int col = n0v + wc * 64 + nf * 16 + lm;
        const float bb = b2[p * DOUT + col];
#pragma unroll
        for (int mf = 0; mf < 2; ++mf) {
#pragma unroll
            for (int j = 0; j < 4; ++j) {
                const int tok = wr * 32 + mf * 16 + lk * 4 + j;
                if (m0 + tok < cnt)
                    out[(size_t)perm[off + m0 + tok] * DOUT + col] = acc[mf][nf][j] + bb;
            }
        }
    }
}

// ---------------- launch ----------------
extern "C" void kernel_launch(void* const* d_in, const int* in_sizes, int n_in,
                              void* d_out, int out_size, void* d_ws, size_t ws_size,
                              hipStream_t stream) {
    const float* x    = (const float*)d_in[0];
    const float* W1   = (const float*)d_in[1];
    const float* b1   = (const float*)d_in[2];
    const float* W2   = (const float*)d_in[3];
    const float* b2   = (const float*)d_in[4];
    const int*   pidx = (const int*)d_in[5];
    float*       out  = (float*)d_out;

    char* ws      = (char*)d_ws;
    int* offsets  = (int*)(ws + WS_OFFSETS);
    int* blkhist  = (int*)(ws + WS_BLKHIST);
    int* perm     = (int*)(ws + WS_PERM);
    u16* xb       = (u16*)(ws + WS_XB);
    u16* w1b      = (u16*)(ws + WS_W1B);
    u16* w2b      = (u16*)(ws + WS_W2B);
    u16* hb       = (u16*)(ws + WS_HB);

    prep_k<<<2048, 256, 0, stream>>>(pidx, x, W1, W2, blkhist, xb, w1b, w2b);
    scatter_k<<<NBLK, 256, 0, stream>>>(pidx, blkhist, offsets, perm);

    // ntiles <= 519 -> tn <= 66/xcd
    // gemm1: NSPLIT=8 (128-col chunks of DHID) -> 8*66*8 = 4224 slots
    gemm1_k<<<4224, 256, 0, stream>>>(xb, w1b, b1, perm, offsets, hb);
    // gemm2: NSPLIT=2 (128-col chunks of DOUT) -> 8*66*2 = 1056 slots
    gemm2_k<<<1056, 256, 0, stream>>>(hb, w2b, b2, perm, offsets, out);
}

// Round 16
// 105.243 us; speedup vs baseline: 2.0505x; 1.0458x over previous
//
#include <hip/hip_runtime.h>
#include <hip/hip_fp16.h>
#include <cstdint>

#define NT      32768
#define DIN     256
#define DHID    1024
#define DOUT    256
#define NPLANES 8
#define NBLK    (NT / 256)

typedef unsigned short u16;
typedef __attribute__((ext_vector_type(8))) _Float16 f16x8;
typedef __attribute__((ext_vector_type(4))) float    f32x4;

// ---------------- workspace layout (bytes) ----------------
#define WS_OFFSETS 0                           // 9 ints (scatter_k blk 0)
#define WS_META    64                          // 1 int: ntiles (64-gran)
#define WS_TP      1024                        // <=544 ints
#define WS_TM      (WS_TP + 544*4)
#define WS_BLKHIST (WS_TM + 544*4)
#define WS_PERM    (WS_BLKHIST + NBLK*8*4)     // NT ints
#define WS_XB      (WS_PERM + NT*4)            // NT*DIN f16, natural order
#define WS_W1B     (WS_XB + NT*DIN*2)
#define WS_W2B     (WS_W1B + NPLANES*DHID*DIN*2)
#define WS_HB      (WS_W2B + NPLANES*DOUT*DHID*2)   // NT*DHID f16, bucketed

__device__ __forceinline__ u16 f2h_bits(float f) {
    __half h = __float2half(f);
    return *reinterpret_cast<u16*>(&h);
}

__device__ __forceinline__ void gl_lds16(const void* g, void* l) {
    __builtin_amdgcn_global_load_lds(
        (const __attribute__((address_space(1))) void*)g,
        (__attribute__((address_space(3))) void*)l,
        16, 0, 0);
}

// fast gelu: tanh-form, |dev vs exact erf-gelu| <~ 5e-4 (negligible after W2)
__device__ __forceinline__ float gelu_fast(float x) {
    const float u = x * (1.5957691216f + 0.07135481283f * x * x);
    const float e = __expf(-u);
    return x * __builtin_amdgcn_rcpf(1.0f + e);
}

// ---------------- prep: per-block hist + f32->f16 converts ----------
__global__ void prep_k(const int* __restrict__ pidx, const float* __restrict__ x,
                       const float* __restrict__ W1, const float* __restrict__ W2,
                       int* __restrict__ blkhist, u16* __restrict__ xb,
                       u16* __restrict__ w1b, u16* __restrict__ w2b) {
    __shared__ int cnt[NPLANES];
    const int t = threadIdx.x, lane = t & 63;
    if ((int)blockIdx.x < NBLK) {
        if (t < NPLANES) cnt[t] = 0;
        __syncthreads();
        const int p = pidx[blockIdx.x * 256 + t];
#pragma unroll
        for (int q = 0; q < NPLANES; ++q) {
            unsigned long long m = __ballot(p == q);
            if (p == q && __popcll(m & ((1ULL << lane) - 1)) == 0)
                atomicAdd(&cnt[q], __popcll(m));
        }
        __syncthreads();
        if (t < NPLANES) blkhist[blockIdx.x * NPLANES + t] = cnt[t];
    }
    const int n0 = NT * DIN / 4, n1 = NPLANES * DHID * DIN / 4, n2 = NPLANES * DOUT * DHID / 4;
    const int stride = gridDim.x * blockDim.x;
    for (int i = blockIdx.x * blockDim.x + t; i < n0 + n1 + n2; i += stride) {
        const float4* s; ushort4* d; int j;
        if (i < n0)           { s = (const float4*)x;  d = (ushort4*)xb;  j = i; }
        else if (i < n0 + n1) { s = (const float4*)W1; d = (ushort4*)w1b; j = i - n0; }
        else                  { s = (const float4*)W2; d = (ushort4*)w2b; j = i - n0 - n1; }
        float4 v = s[j];
        ushort4 o;
        o.x = f2h_bits(v.x); o.y = f2h_bits(v.y);
        o.z = f2h_bits(v.z); o.w = f2h_bits(v.w);
        d[j] = o;
    }
}

// ---------------- scatter + inline scan + parallel tile-list build ------------
// Every block: plane totals + own prefix from blkhist (4KB, L2-hot) -> scatter.
// Block 0 additionally publishes offsets[9], meta[0]=ntiles, and tp/tm built
// in PARALLEL (8 threads x <=65 iters; kills R14's serial 520-step loop).
__global__ void scatter_k(const int* __restrict__ pidx, const int* __restrict__ blkhist,
                          int* __restrict__ offsets, int* __restrict__ meta,
                          int* __restrict__ tp, int* __restrict__ tm,
                          int* __restrict__ perm) {
    __shared__ int stot[NPLANES], spre[NPLANES], sbase[NPLANES];
    __shared__ int wcnt[4][NPLANES], wbase[4][NPLANES];
    const int t = threadIdx.x, lane = t & 63, wave = t >> 6;
    if (t < NPLANES) {
        int tot = 0, pre = 0;
        for (int b = 0; b < NBLK; ++b) {
            const int v = blkhist[b * NPLANES + t];
            tot += v;
            if (b < (int)blockIdx.x) pre += v;
        }
        stot[t] = tot; spre[t] = pre;
    }
    __syncthreads();
    if (t == 0) {
        int run = 0;
        for (int q = 0; q < NPLANES; ++q) {
            sbase[q] = run + spre[q];
            if (blockIdx.x == 0) offsets[q] = run;
            run += stot[q];
        }
        if (blockIdx.x == 0) offsets[NPLANES] = run;
    }
    __syncthreads();
    if (blockIdx.x == 0 && t < NPLANES) {
        // parallel tile-list build: thread t handles plane t
        int pre = 0, ntiles = 0;
#pragma unroll
        for (int q = 0; q < NPLANES; ++q) {
            const int ntq = (stot[q] + 63) >> 6;
            if (q < t) pre += ntq;
            ntiles += ntq;
        }
        for (int m = 0, i = pre; m < stot[t]; m += 64, ++i) { tp[i] = t; tm[i] = m; }
        if (t == 0) meta[0] = ntiles;
    }
    const int i = blockIdx.x * 256 + t;
    const int p = pidx[i];
    int rank = 0;
#pragma unroll
    for (int q = 0; q < NPLANES; ++q) {
        unsigned long long m = __ballot(p == q);
        if (lane == 0) wcnt[wave][q] = __popcll(m);
        if (p == q) rank = __popcll(m & ((1ULL << lane) - 1));
    }
    __syncthreads();
    if (t < NPLANES) {
        int run = sbase[t];
#pragma unroll
        for (int w = 0; w < 4; ++w) { wbase[w][t] = run; run += wcnt[w][t]; }
    }
    __syncthreads();
    perm[wbase[wave][p] + rank] = i;
}

// XCD-chunked tile mapping (VERIFIED R6: XCD = linear_block_id % 8).
#define XCD_MAP(NSPLIT)                                                        \
    const int ntiles = meta[0];                                                \
    const int xcd = blockIdx.x & 7, idx = blockIdx.x >> 3;                     \
    const int q8 = ntiles >> 3, r8 = ntiles & 7;                               \
    const int tn = q8 + (xcd < r8 ? 1 : 0);                                    \
    if (idx >= tn * (NSPLIT)) return;                                          \
    const int tile = (xcd < r8 ? xcd * (q8 + 1)                                \
                               : r8 * (q8 + 1) + (xcd - r8) * q8)              \
                     + idx / (NSPLIT);                                         \
    const int sub = idx % (NSPLIT);                                            \
    const int p   = tp[tile];                                                  \
    const int m0  = tm[tile];                                                  \
    const int off = offsets[p];                                                \
    const int cnt = offsets[p + 1] - off;

// ---------------- gemm1: R7-exact (64x128 tile, BK=64, 24KB, best 45.4us) ----
__global__ __launch_bounds__(256, 6) void gemm1_k(
    const u16* __restrict__ xb, const u16* __restrict__ w1b,
    const float* __restrict__ b1, const int* __restrict__ perm,
    const int* __restrict__ offsets, const int* __restrict__ meta,
    const int* __restrict__ tp, const int* __restrict__ tm,
    u16* __restrict__ hb)
{
    __shared__ __align__(16) u16 smem[12288];   // sA 8KB | sB 16KB; sOut 16KB reuse
    XCD_MAP(8)
    const int n0v = sub * 128;

    u16* const sA = smem;
    u16* const sB = smem + 4096;

    const int tid = threadIdx.x;
    const u16* aptr[2];
    const u16* bptr[4];
#pragma unroll
    for (int c = 0; c < 2; ++c) {
        const int slot = c * 256 + tid, row = slot >> 3, ch = slot & 7;
        const int gr = min(m0 + row, cnt - 1);
        aptr[c] = xb + (size_t)perm[off + gr] * DIN + ((ch ^ (row & 7)) * 8);
    }
#pragma unroll
    for (int c = 0; c < 4; ++c) {
        const int slot = c * 256 + tid, row = slot >> 3, ch = slot & 7;
        bptr[c] = w1b + ((size_t)p * DHID + n0v + row) * DIN + ((ch ^ (row & 7)) * 8);
    }
    const int wave = tid >> 6, lane = tid & 63;
    const int wr = wave >> 1, wc = wave & 1;    // 2x2 waves, wave tile 32x64
    const int lm = lane & 15, lk = lane >> 4;

    f32x4 acc[2][4];
#pragma unroll
    for (int a = 0; a < 2; ++a)
#pragma unroll
        for (int b = 0; b < 4; ++b) acc[a][b] = (f32x4){0.f, 0.f, 0.f, 0.f};

    for (int kt = 0; kt < DIN / 64; ++kt) {
        const int k0 = kt * 64;
#pragma unroll
        for (int c = 0; c < 2; ++c) gl_lds16(aptr[c] + k0, sA + c * 2048 + tid * 8);
#pragma unroll
        for (int c = 0; c < 4; ++c) gl_lds16(bptr[c] + k0, sB + c * 2048 + tid * 8);
        __syncthreads();
#pragma unroll
        for (int kk = 0; kk < 2; ++kk) {
            f16x8 af[2], bf[4];
#pragma unroll
            for (int mf = 0; mf < 2; ++mf) {
                const int row = wr * 32 + mf * 16 + lm;
                const int g   = kk * 4 + lk;
                af[mf] = *(const f16x8*)(sA + row * 64 + ((g ^ (row & 7)) * 8));
            }
#pragma unroll
            for (int nf = 0; nf < 4; ++nf) {
                const int row = wc * 64 + nf * 16 + lm;
                const int g   = kk * 4 + lk;
                bf[nf] = *(const f16x8*)(sB + row * 64 + ((g ^ (row & 7)) * 8));
            }
#pragma unroll
            for (int mf = 0; mf < 2; ++mf)
#pragma unroll
                for (int nf = 0; nf < 4; ++nf)
                    acc[mf][nf] = __builtin_amdgcn_mfma_f32_16x16x32_f16(
                        af[mf], bf[nf], acc[mf][nf], 0, 0, 0);
        }
        __syncthreads();
    }

    // ---- epilogue: fast gelu -> chunk-swizzled sOut, then coalesced copy-out ----
    u16* const sOut = smem;                     // 64 x 128 u16 = 16KB
#pragma unroll
    for (int nf = 0; nf < 4; ++nf) {
        const int col = wc * 64 + nf * 16 + lm;
        const float bb = b1[p * DHID + n0v + col];
        const int cc = col >> 3, c7 = col & 7;
#pragma unroll
        for (int mf = 0; mf < 2; ++mf) {
#pragma unroll
            for (int j = 0; j < 4; ++j) {
                const int tok = wr * 32 + mf * 16 + lk * 4 + j;
                sOut[tok * 128 + ((cc ^ (tok & 15)) * 8) + c7] =
                    f2h_bits(gelu_fast(acc[mf][nf][j] + bb));
            }
        }
    }
    __syncthreads();
    const int r = tid >> 2, qq = tid & 3;       // 4 threads/row, 64B each
    if (m0 + r < cnt) {
        u16* dst = hb + (size_t)(off + m0 + r) * DHID + n0v;
#pragma unroll
        for (int c = 0; c < 4; ++c) {
            const int l = qq * 4 + c;
            *(int4*)(dst + l * 8) = *(const int4*)(sOut + r * 128 + ((l ^ (r & 15)) * 8));
        }
    }
}

// ---------------- gemm2: R9-exact (64x128 tile, BK=128, KT=8, 48KB) ----------
__global__ __launch_bounds__(256, 3) void gemm2_k(
    const u16* __restrict__ hb, const u16* __restrict__ w2b,
    const float* __restrict__ b2, const int* __restrict__ perm,
    const int* __restrict__ offsets, const int* __restrict__ meta,
    const int* __restrict__ tp, const int* __restrict__ tm,
    float* __restrict__ out)
{
    __shared__ __align__(16) u16 smem[24576];   // sA 16KB | sB 32KB
    XCD_MAP(2)
    const int n0v = sub * 128;

    u16* const sA = smem;
    u16* const sB = smem + 8192;

    const int tid = threadIdx.x;
    const u16* aptr[4];
#pragma unroll
    for (int c = 0; c < 4; ++c) {
        const int slot = c * 256 + tid, row = slot >> 4, ch = slot & 15;
        aptr[c] = hb + (size_t)(off + min(m0 + row, cnt - 1)) * DHID + ((ch ^ (row & 15)) * 8);
    }
    const u16* bptr[8];
#pragma unroll
    for (int c = 0; c < 8; ++c) {
        const int slot = c * 256 + tid, row = slot >> 4, ch = slot & 15;
        bptr[c] = w2b + ((size_t)p * DOUT + n0v + row) * DHID + ((ch ^ (row & 15)) * 8);
    }
    const int wave = tid >> 6, lane = tid & 63;
    const int wr = wave >> 1, wc = wave & 1;    // 2x2 waves, wave tile 32x64
    const int lm = lane & 15, lk = lane >> 4;

    f32x4 acc[2][4];
#pragma unroll
    for (int a = 0; a < 2; ++a)
#pragma unroll
        for (int b = 0; b < 4; ++b) acc[a][b] = (f32x4){0.f, 0.f, 0.f, 0.f};

    for (int kt = 0; kt < DHID / 128; ++kt) {   // 8 K-steps
        const int k0 = kt * 128;
#pragma unroll
        for (int c = 0; c < 4; ++c) gl_lds16(aptr[c] + k0, sA + c * 2048 + tid * 8);
#pragma unroll
        for (int c = 0; c < 8; ++c) gl_lds16(bptr[c] + k0, sB + c * 2048 + tid * 8);
        __syncthreads();
#pragma unroll
        for (int kk = 0; kk < 4; ++kk) {
            f16x8 af[2], bf[4];
#pragma unroll
            for (int mf = 0; mf < 2; ++mf) {
                const int row = wr * 32 + mf * 16 + lm;
                const int g   = kk * 4 + lk;
                af[mf] = *(const f16x8*)(sA + row * 128 + ((g ^ (row & 15)) * 8));
            }
#pragma unroll
            for (int nf = 0; nf < 4; ++nf) {
                const int row = wc * 64 + nf * 16 + lm;
                const int g   = kk * 4 + lk;
                bf[nf] = *(const f16x8*)(sB + row * 128 + ((g ^ (row & 15)) * 8));
            }
#pragma unroll
            for (int mf = 0; mf < 2; ++mf)
#pragma unroll
                for (int nf = 0; nf < 4; ++nf)
                    acc[mf][nf] = __builtin_amdgcn_mfma_f32_16x16x32_f16(
                        af[mf], bf[nf], acc[mf][nf], 0, 0, 0);
        }
        __syncthreads();
    }

#pragma unroll
    for (int nf = 0; nf < 4; ++nf) {
        const int col = n0v + wc * 64 + nf * 16 + lm;
        const float bb = b2[p * DOUT + col];
#pragma unroll
        for (int mf = 0; mf < 2; ++mf) {
#pragma unroll
            for (int j = 0; j < 4; ++j) {
                const int tok = wr * 32 + mf * 16 + lk * 4 + j;
                if (m0 + tok < cnt)
                    out[(size_t)perm[off + m0 + tok] * DOUT + col] = acc[mf][nf][j] + bb;
            }
        }
    }
}

// ---------------- launch ----------------
extern "C" void kernel_launch(void* const* d_in, const int* in_sizes, int n_in,
                              void* d_out, int out_size, void* d_ws, size_t ws_size,
                              hipStream_t stream) {
    const float* x    = (const float*)d_in[0];
    const float* W1   = (const float*)d_in[1];
    const float* b1   = (const float*)d_in[2];
    const float* W2   = (const float*)d_in[3];
    const float* b2   = (const float*)d_in[4];
    const int*   pidx = (const int*)d_in[5];
    float*       out  = (float*)d_out;

    char* ws      = (char*)d_ws;
    int* offsets  = (int*)(ws + WS_OFFSETS);
    int* meta     = (int*)(ws + WS_META);
    int* tp       = (int*)(ws + WS_TP);
    int* tm       = (int*)(ws + WS_TM);
    int* blkhist  = (int*)(ws + WS_BLKHIST);
    int* perm     = (int*)(ws + WS_PERM);
    u16* xb       = (u16*)(ws + WS_XB);
    u16* w1b      = (u16*)(ws + WS_W1B);
    u16* w2b      = (u16*)(ws + WS_W2B);
    u16* hb       = (u16*)(ws + WS_HB);

    prep_k<<<2048, 256, 0, stream>>>(pidx, x, W1, W2, blkhist, xb, w1b, w2b);
    scatter_k<<<NBLK, 256, 0, stream>>>(pidx, blkhist, offsets, meta, tp, tm, perm);

    // ntiles <= 519 -> tn <= 66/xcd
    // gemm1: NSPLIT=8 (128-col chunks of DHID) -> 8*66*8 = 4224 slots
    gemm1_k<<<4224, 256, 0, stream>>>(xb, w1b, b1, perm, offsets, meta, tp, tm, hb);
    // gemm2: NSPLIT=2 (128-col chunks of DOUT) -> 8*66*2 = 1056 slots
    gemm2_k<<<1056, 256, 0, stream>>>(hb, w2b, b2, perm, offsets, meta, tp, tm, out);
}

// Round 17
// 102.065 us; speedup vs baseline: 2.1143x; 1.0311x over previous
//
#include <hip/hip_runtime.h>
#include <hip/hip_fp16.h>
#include <cstdint>

#define NT      32768
#define DIN     256
#define DHID    1024
#define DOUT    256
#define NPLANES 8
#define NBLK    (NT / 256)

typedef unsigned short u16;
typedef __attribute__((ext_vector_type(8))) _Float16 f16x8;
typedef __attribute__((ext_vector_type(4))) float    f32x4;

// ---------------- workspace layout (bytes) ----------------
#define WS_OFFSETS 0                           // 9 ints (scatter_k blk 0)
#define WS_META    64                          // 1 int: ntiles (64-gran)
#define WS_TP      1024                        // <=544 ints
#define WS_TM      (WS_TP + 544*4)
#define WS_BLKHIST (WS_TM + 544*4)
#define WS_PERM    (WS_BLKHIST + NBLK*8*4)     // NT ints
#define WS_XB      (WS_PERM + NT*4)            // NT*DIN f16, natural order
#define WS_W1B     (WS_XB + NT*DIN*2)
#define WS_W2B     (WS_W1B + NPLANES*DHID*DIN*2)
#define WS_HB      (WS_W2B + NPLANES*DOUT*DHID*2)   // NT*DHID f16, bucketed

__device__ __forceinline__ u16 f2h_bits(float f) {
    __half h = __float2half(f);
    return *reinterpret_cast<u16*>(&h);
}

__device__ __forceinline__ void gl_lds16(const void* g, void* l) {
    __builtin_amdgcn_global_load_lds(
        (const __attribute__((address_space(1))) void*)g,
        (__attribute__((address_space(3))) void*)l,
        16, 0, 0);
}

// fast gelu: tanh-form, |dev vs exact erf-gelu| <~ 5e-4 (negligible after W2)
__device__ __forceinline__ float gelu_fast(float x) {
    const float u = x * (1.5957691216f + 0.07135481283f * x * x);
    const float e = __expf(-u);
    return x * __builtin_amdgcn_rcpf(1.0f + e);
}

// ---------------- prep: per-block hist + f32->f16 converts ----------
__global__ void prep_k(const int* __restrict__ pidx, const float* __restrict__ x,
                       const float* __restrict__ W1, const float* __restrict__ W2,
                       int* __restrict__ blkhist, u16* __restrict__ xb,
                       u16* __restrict__ w1b, u16* __restrict__ w2b) {
    __shared__ int cnt[NPLANES];
    const int t = threadIdx.x, lane = t & 63;
    if ((int)blockIdx.x < NBLK) {
        if (t < NPLANES) cnt[t] = 0;
        __syncthreads();
        const int p = pidx[blockIdx.x * 256 + t];
#pragma unroll
        for (int q = 0; q < NPLANES; ++q) {
            unsigned long long m = __ballot(p == q);
            if (p == q && __popcll(m & ((1ULL << lane) - 1)) == 0)
                atomicAdd(&cnt[q], __popcll(m));
        }
        __syncthreads();
        if (t < NPLANES) blkhist[blockIdx.x * NPLANES + t] = cnt[t];
    }
    const int n0 = NT * DIN / 4, n1 = NPLANES * DHID * DIN / 4, n2 = NPLANES * DOUT * DHID / 4;
    const int stride = gridDim.x * blockDim.x;
    for (int i = blockIdx.x * blockDim.x + t; i < n0 + n1 + n2; i += stride) {
        const float4* s; ushort4* d; int j;
        if (i < n0)           { s = (const float4*)x;  d = (ushort4*)xb;  j = i; }
        else if (i < n0 + n1) { s = (const float4*)W1; d = (ushort4*)w1b; j = i - n0; }
        else                  { s = (const float4*)W2; d = (ushort4*)w2b; j = i - n0 - n1; }
        float4 v = s[j];
        ushort4 o;
        o.x = f2h_bits(v.x); o.y = f2h_bits(v.y);
        o.z = f2h_bits(v.z); o.w = f2h_bits(v.w);
        d[j] = o;
    }
}

// ---------------- scatter + inline scan + parallel tile-list build ------------
__global__ void scatter_k(const int* __restrict__ pidx, const int* __restrict__ blkhist,
                          int* __restrict__ offsets, int* __restrict__ meta,
                          int* __restrict__ tp, int* __restrict__ tm,
                          int* __restrict__ perm) {
    __shared__ int stot[NPLANES], spre[NPLANES], sbase[NPLANES];
    __shared__ int wcnt[4][NPLANES], wbase[4][NPLANES];
    const int t = threadIdx.x, lane = t & 63, wave = t >> 6;
    if (t < NPLANES) {
        int tot = 0, pre = 0;
        for (int b = 0; b < NBLK; ++b) {
            const int v = blkhist[b * NPLANES + t];
            tot += v;
            if (b < (int)blockIdx.x) pre += v;
        }
        stot[t] = tot; spre[t] = pre;
    }
    __syncthreads();
    if (t == 0) {
        int run = 0;
        for (int q = 0; q < NPLANES; ++q) {
            sbase[q] = run + spre[q];
            if (blockIdx.x == 0) offsets[q] = run;
            run += stot[q];
        }
        if (blockIdx.x == 0) offsets[NPLANES] = run;
    }
    __syncthreads();
    if (blockIdx.x == 0 && t < NPLANES) {
        int pre = 0, ntiles = 0;
#pragma unroll
        for (int q = 0; q < NPLANES; ++q) {
            const int ntq = (stot[q] + 63) >> 6;
            if (q < t) pre += ntq;
            ntiles += ntq;
        }
        for (int m = 0, i = pre; m < stot[t]; m += 64, ++i) { tp[i] = t; tm[i] = m; }
        if (t == 0) meta[0] = ntiles;
    }
    const int i = blockIdx.x * 256 + t;
    const int p = pidx[i];
    int rank = 0;
#pragma unroll
    for (int q = 0; q < NPLANES; ++q) {
        unsigned long long m = __ballot(p == q);
        if (lane == 0) wcnt[wave][q] = __popcll(m);
        if (p == q) rank = __popcll(m & ((1ULL << lane) - 1));
    }
    __syncthreads();
    if (t < NPLANES) {
        int run = sbase[t];
#pragma unroll
        for (int w = 0; w < 4; ++w) { wbase[w][t] = run; run += wcnt[w][t]; }
    }
    __syncthreads();
    perm[wbase[wave][p] + rank] = i;
}

// XCD-chunked tile mapping (VERIFIED R6: XCD = linear_block_id % 8).
#define XCD_MAP(NSPLIT)                                                        \
    const int ntiles = meta[0];                                                \
    const int xcd = blockIdx.x & 7, idx = blockIdx.x >> 3;                     \
    const int q8 = ntiles >> 3, r8 = ntiles & 7;                               \
    const int tn = q8 + (xcd < r8 ? 1 : 0);                                    \
    if (idx >= tn * (NSPLIT)) return;                                          \
    const int tile = (xcd < r8 ? xcd * (q8 + 1)                                \
                               : r8 * (q8 + 1) + (xcd - r8) * q8)              \
                     + idx / (NSPLIT);                                         \
    const int sub = idx % (NSPLIT);                                            \
    const int p   = tp[tile];                                                  \
    const int m0  = tm[tile];                                                  \
    const int off = offsets[p];                                                \
    const int cnt = offsets[p + 1] - off;

// ---------------- gemm1: R16-exact (64x128 tile, BK=64, 24KB, 6 blk/CU) ------
__global__ __launch_bounds__(256, 6) void gemm1_k(
    const u16* __restrict__ xb, const u16* __restrict__ w1b,
    const float* __restrict__ b1, const int* __restrict__ perm,
    const int* __restrict__ offsets, const int* __restrict__ meta,
    const int* __restrict__ tp, const int* __restrict__ tm,
    u16* __restrict__ hb)
{
    __shared__ __align__(16) u16 smem[12288];   // sA 8KB | sB 16KB; sOut 16KB reuse
    XCD_MAP(8)
    const int n0v = sub * 128;

    u16* const sA = smem;
    u16* const sB = smem + 4096;

    const int tid = threadIdx.x;
    const u16* aptr[2];
    const u16* bptr[4];
#pragma unroll
    for (int c = 0; c < 2; ++c) {
        const int slot = c * 256 + tid, row = slot >> 3, ch = slot & 7;
        const int gr = min(m0 + row, cnt - 1);
        aptr[c] = xb + (size_t)perm[off + gr] * DIN + ((ch ^ (row & 7)) * 8);
    }
#pragma unroll
    for (int c = 0; c < 4; ++c) {
        const int slot = c * 256 + tid, row = slot >> 3, ch = slot & 7;
        bptr[c] = w1b + ((size_t)p * DHID + n0v + row) * DIN + ((ch ^ (row & 7)) * 8);
    }
    const int wave = tid >> 6, lane = tid & 63;
    const int wr = wave >> 1, wc = wave & 1;    // 2x2 waves, wave tile 32x64
    const int lm = lane & 15, lk = lane >> 4;

    f32x4 acc[2][4];
#pragma unroll
    for (int a = 0; a < 2; ++a)
#pragma unroll
        for (int b = 0; b < 4; ++b) acc[a][b] = (f32x4){0.f, 0.f, 0.f, 0.f};

    for (int kt = 0; kt < DIN / 64; ++kt) {
        const int k0 = kt * 64;
#pragma unroll
        for (int c = 0; c < 2; ++c) gl_lds16(aptr[c] + k0, sA + c * 2048 + tid * 8);
#pragma unroll
        for (int c = 0; c < 4; ++c) gl_lds16(bptr[c] + k0, sB + c * 2048 + tid * 8);
        __syncthreads();
#pragma unroll
        for (int kk = 0; kk < 2; ++kk) {
            f16x8 af[2], bf[4];
#pragma unroll
            for (int mf = 0; mf < 2; ++mf) {
                const int row = wr * 32 + mf * 16 + lm;
                const int g   = kk * 4 + lk;
                af[mf] = *(const f16x8*)(sA + row * 64 + ((g ^ (row & 7)) * 8));
            }
#pragma unroll
            for (int nf = 0; nf < 4; ++nf) {
                const int row = wc * 64 + nf * 16 + lm;
                const int g   = kk * 4 + lk;
                bf[nf] = *(const f16x8*)(sB + row * 64 + ((g ^ (row & 7)) * 8));
            }
#pragma unroll
            for (int mf = 0; mf < 2; ++mf)
#pragma unroll
                for (int nf = 0; nf < 4; ++nf)
                    acc[mf][nf] = __builtin_amdgcn_mfma_f32_16x16x32_f16(
                        af[mf], bf[nf], acc[mf][nf], 0, 0, 0);
        }
        __syncthreads();
    }

    // ---- epilogue: fast gelu -> chunk-swizzled sOut, then coalesced copy-out ----
    u16* const sOut = smem;                     // 64 x 128 u16 = 16KB
#pragma unroll
    for (int nf = 0; nf < 4; ++nf) {
        const int col = wc * 64 + nf * 16 + lm;
        const float bb = b1[p * DHID + n0v + col];
        const int cc = col >> 3, c7 = col & 7;
#pragma unroll
        for (int mf = 0; mf < 2; ++mf) {
#pragma unroll
            for (int j = 0; j < 4; ++j) {
                const int tok = wr * 32 + mf * 16 + lk * 4 + j;
                sOut[tok * 128 + ((cc ^ (tok & 15)) * 8) + c7] =
                    f2h_bits(gelu_fast(acc[mf][nf][j] + bb));
            }
        }
    }
    __syncthreads();
    const int r = tid >> 2, qq = tid & 3;       // 4 threads/row, 64B each
    if (m0 + r < cnt) {
        u16* dst = hb + (size_t)(off + m0 + r) * DHID + n0v;
#pragma unroll
        for (int c = 0; c < 4; ++c) {
            const int l = qq * 4 + c;
            *(int4*)(dst + l * 8) = *(const int4*)(sOut + r * 128 + ((l ^ (r & 15)) * 8));
        }
    }
}

// ---------------- gemm2: BK=64, 24KB, launch_bounds(256,6) — occupancy test ---
// Same wave structure as gemm1 (2x2 waves of 32x64), KT=16. LDS allows 6
// blocks/CU (vs 3 for the 48KB BK=128 variant); grid 1056 => ~4.1/CU resident.
__global__ __launch_bounds__(256, 6) void gemm2_k(
    const u16* __restrict__ hb, const u16* __restrict__ w2b,
    const float* __restrict__ b2, const int* __restrict__ perm,
    const int* __restrict__ offsets, const int* __restrict__ meta,
    const int* __restrict__ tp, const int* __restrict__ tm,
    float* __restrict__ out)
{
    __shared__ __align__(16) u16 smem[12288];   // sA 8KB | sB 16KB
    XCD_MAP(2)
    const int n0v = sub * 128;

    u16* const sA = smem;
    u16* const sB = smem + 4096;

    const int tid = threadIdx.x;
    const u16* aptr[2];
    const u16* bptr[4];
#pragma unroll
    for (int c = 0; c < 2; ++c) {
        const int slot = c * 256 + tid, row = slot >> 3, ch = slot & 7;
        aptr[c] = hb + (size_t)(off + min(m0 + row, cnt - 1)) * DHID + ((ch ^ (row & 7)) * 8);
    }
#pragma unroll
    for (int c = 0; c < 4; ++c) {
        const int slot = c * 256 + tid, row = slot >> 3, ch = slot & 7;
        bptr[c] = w2b + ((size_t)p * DOUT + n0v + row) * DHID + ((ch ^ (row & 7)) * 8);
    }
    const int wave = tid >> 6, lane = tid & 63;
    const int wr = wave >> 1, wc = wave & 1;    // 2x2 waves, wave tile 32x64
    const int lm = lane & 15, lk = lane >> 4;

    f32x4 acc[2][4];
#pragma unroll
    for (int a = 0; a < 2; ++a)
#pragma unroll
        for (int b = 0; b < 4; ++b) acc[a][b] = (f32x4){0.f, 0.f, 0.f, 0.f};

    for (int kt = 0; kt < DHID / 64; ++kt) {    // 16 K-steps
        const int k0 = kt * 64;
#pragma unroll
        for (int c = 0; c < 2; ++c) gl_lds16(aptr[c] + k0, sA + c * 2048 + tid * 8);
#pragma unroll
        for (int c = 0; c < 4; ++c) gl_lds16(bptr[c] + k0, sB + c * 2048 + tid * 8);
        __syncthreads();
#pragma unroll
        for (int kk = 0; kk < 2; ++kk) {
            f16x8 af[2], bf[4];
#pragma unroll
            for (int mf = 0; mf < 2; ++mf) {
                const int row = wr * 32 + mf * 16 + lm;
                const int g   = kk * 4 + lk;
                af[mf] = *(const f16x8*)(sA + row * 64 + ((g ^ (row & 7)) * 8));
            }
#pragma unroll
            for (int nf = 0; nf < 4; ++nf) {
                const int row = wc * 64 + nf * 16 + lm;
                const int g   = kk * 4 + lk;
                bf[nf] = *(const f16x8*)(sB + row * 64 + ((g ^ (row & 7)) * 8));
            }
#pragma unroll
            for (int mf = 0; mf < 2; ++mf)
#pragma unroll
                for (int nf = 0; nf < 4; ++nf)
                    acc[mf][nf] = __builtin_amdgcn_mfma_f32_16x16x32_f16(
                        af[mf], bf[nf], acc[mf][nf], 0, 0, 0);
        }
        __syncthreads();
    }

#pragma unroll
    for (int nf = 0; nf < 4; ++nf) {
        const int col = n0v + wc * 64 + nf * 16 + lm;
        const float bb = b2[p * DOUT + col];
#pragma unroll
        for (int mf = 0; mf < 2; ++mf) {
#pragma unroll
            for (int j = 0; j < 4; ++j) {
                const int tok = wr * 32 + mf * 16 + lk * 4 + j;
                if (m0 + tok < cnt)
                    out[(size_t)perm[off + m0 + tok] * DOUT + col] = acc[mf][nf][j] + bb;
            }
        }
    }
}

// ---------------- launch ----------------
extern "C" void kernel_launch(void* const* d_in, const int* in_sizes, int n_in,
                              void* d_out, int out_size, void* d_ws, size_t ws_size,
                              hipStream_t stream) {
    const float* x    = (const float*)d_in[0];
    const float* W1   = (const float*)d_in[1];
    const float* b1   = (const float*)d_in[2];
    const float* W2   = (const float*)d_in[3];
    const float* b2   = (const float*)d_in[4];
    const int*   pidx = (const int*)d_in[5];
    float*       out  = (float*)d_out;

    char* ws      = (char*)d_ws;
    int* offsets  = (int*)(ws + WS_OFFSETS);
    int* meta     = (int*)(ws + WS_META);
    int* tp       = (int*)(ws + WS_TP);
    int* tm       = (int*)(ws + WS_TM);
    int* blkhist  = (int*)(ws + WS_BLKHIST);
    int* perm     = (int*)(ws + WS_PERM);
    u16* xb       = (u16*)(ws + WS_XB);
    u16* w1b      = (u16*)(ws + WS_W1B);
    u16* w2b      = (u16*)(ws + WS_W2B);
    u16* hb       = (u16*)(ws + WS_HB);

    prep_k<<<2048, 256, 0, stream>>>(pidx, x, W1, W2, blkhist, xb, w1b, w2b);
    scatter_k<<<NBLK, 256, 0, stream>>>(pidx, blkhist, offsets, meta, tp, tm, perm);

    // ntiles <= 519 -> tn <= 66/xcd
    // gemm1: NSPLIT=8 (128-col chunks of DHID) -> 8*66*8 = 4224 slots
    gemm1_k<<<4224, 256, 0, stream>>>(xb, w1b, b1, perm, offsets, meta, tp, tm, hb);
    // gemm2: NSPLIT=2 (128-col chunks of DOUT) -> 8*66*2 = 1056 slots
    gemm2_k<<<1056, 256, 0, stream>>>(hb, w2b, b2, perm, offsets, meta, tp, tm, out);
}